// Round 1
// baseline (779.305 us; speedup 1.0000x reference)
//
#include <hip/hip_runtime.h>
#include <hip/hip_bf16.h>
#include <stdint.h>

#define B_ROWS 16384
#define DIM 2048
#define BM 128
#define BN 128
#define BK 64

typedef float f32x4 __attribute__((ext_vector_type(4)));
typedef short bf16x8 __attribute__((ext_vector_type(8)));

__device__ __forceinline__ unsigned int pack_bf2(float a, float b) {
  __hip_bfloat162 t = __float22bfloat162_rn(float2{a, b});
  union { __hip_bfloat162 b2; unsigned int u; } cv;
  cv.b2 = t;
  return cv.u;
}

__device__ __forceinline__ unsigned short f2bf_rne(float f) {
  union { float f; unsigned int u; } v;
  v.f = f;
  unsigned int u = v.u;
  unsigned int r = u + 0x7FFFu + ((u >> 16) & 1u);
  return (unsigned short)(r >> 16);
}

// -------- kernel 1: per-row branch flags (fp64-exact last-column dot) --------
__global__ __launch_bounds__(256) void k_flags(const float* __restrict__ x,
                                               const float* __restrict__ h,
                                               const float* __restrict__ W_ih,
                                               int* __restrict__ flags) {
  int row = blockIdx.x * 4 + (threadIdx.x >> 6);
  int lane = threadIdx.x & 63;
  const float* xr = x + (size_t)row * DIM;
  const float* wr = W_ih + (size_t)(DIM - 1) * DIM;
  double s = 0.0;
#pragma unroll
  for (int i = 0; i < 8; ++i) {
    int idx = (i * 64 + lane) * 4;
    f32x4 xv = *(const f32x4*)(xr + idx);
    f32x4 wv = *(const f32x4*)(wr + idx);
    s += (double)xv.x * wv.x + (double)xv.y * wv.y +
         (double)xv.z * wv.z + (double)xv.w * wv.w;
  }
#pragma unroll
  for (int off = 32; off > 0; off >>= 1) s += __shfl_xor(s, off);
  if (lane == 0) {
    bool not_trig = (s >= -1.0);
    float hl = h[(size_t)row * DIM + (DIM - 1)];
    int f;
    if (!not_trig) f = 2;        // passthrough: += h
    else if (hl > 0.f) f = 0;    // forward: += h @ W_hh
    else if (hl < 0.f) f = 1;    // inverse: += h @ W_inv
    else f = 3;                  // nothing
    flags[row] = f;
  }
}

// -------- kernel 2: convert W_ih (already [N][K] form) f32 -> bf16 ----------
__global__ __launch_bounds__(256) void k_convert(const float* __restrict__ src,
                                                 unsigned short* __restrict__ dst) {
  size_t i = ((size_t)blockIdx.x * 256 + threadIdx.x) * 4;
  f32x4 v = *(const f32x4*)(src + i);
  unsigned int lo = pack_bf2(v.x, v.y);
  unsigned int hi = pack_bf2(v.z, v.w);
  *(uint2*)(dst + i) = uint2{lo, hi};
}

// -------- kernel 3: transpose+convert [K][N] f32 -> [N][K] bf16 -------------
__global__ __launch_bounds__(256) void k_transpose(const float* __restrict__ src,
                                                   unsigned short* __restrict__ dst) {
  __shared__ float tile[32][33];
  int k0 = blockIdx.x * 32;
  int n0 = blockIdx.y * 32;
  int tx = threadIdx.x & 31;
  int ty = threadIdx.x >> 5;  // 0..7
#pragma unroll
  for (int i = 0; i < 4; ++i)
    tile[ty + 8 * i][tx] = src[(size_t)(k0 + ty + 8 * i) * DIM + n0 + tx];
  __syncthreads();
#pragma unroll
  for (int i = 0; i < 4; ++i)
    dst[(size_t)(n0 + ty + 8 * i) * DIM + k0 + tx] = f2bf_rne(tile[tx][ty + 8 * i]);
}

// -------- kernel 4: fused 3-segment GEMM + branch epilogue ------------------
// out[b,d] = x@Wih^T + (m_fwd h)@Whh + (m_inv h)@Winv + (m_pass ? h : 0)
__global__ __launch_bounds__(256, 2) void k_gemm(
    const float* __restrict__ x, const float* __restrict__ h,
    const unsigned short* __restrict__ Wih,
    const unsigned short* __restrict__ WhhT,
    const unsigned short* __restrict__ WinvT,
    const int* __restrict__ flags,
    float* __restrict__ out) {
  __shared__ char smem[(BM + BN) * BK * 2];  // 32 KB: A tile + B tile, swizzled
  char* sA = smem;
  char* sB = smem + BM * BK * 2;

  // XCD-bijective swizzle: 2048 blocks, 8 XCDs, 256 per XCD (contiguous tiles)
  int o = blockIdx.x;
  int swz = (o & 7) * ((int)gridDim.x >> 3) + (o >> 3);
  int tRow = swz >> 4;   // 128 tile-rows
  int tCol = swz & 15;   // 16 tile-cols
  int brow = tRow * BM;
  int bcol = tCol * BN;

  int t = threadIdx.x;
  int lane = t & 63;
  int wave = t >> 6;
  int wrow = (wave >> 1) * 64;
  int wcol = (wave & 1) * 64;

  f32x4 acc[4][4] = {};

  // A staging: thread handles k-group sc (4 f32), rows sr0 + 16*i
  int sc = t & 15;
  int sr0 = t >> 4;

  // fragment LDS byte offsets (XOR swizzle: byte ^= (row&7)<<4)
  int aOff[4][2], bOff[4][2];
#pragma unroll
  for (int m = 0; m < 4; ++m)
#pragma unroll
    for (int kk = 0; kk < 2; ++kk) {
      int ar = wrow + m * 16 + (lane & 15);
      aOff[m][kk] = ar * (BK * 2) + ((kk * 64 + (lane >> 4) * 16) ^ ((ar & 7) << 4));
      int br = wcol + m * 16 + (lane & 15);
      bOff[m][kk] = br * (BK * 2) + ((kk * 64 + (lane >> 4) * 16) ^ ((br & 7) << 4));
    }

#pragma unroll 1
  for (int seg = 0; seg < 3; ++seg) {
    const float* Asrc = (seg == 0) ? x : h;
    const unsigned short* Bsrc = (seg == 0) ? Wih : (seg == 1) ? WhhT : WinvT;
    int want = seg - 1;  // -1 (no mask), 0 (fwd), 1 (inv)

    float rmask[8];
#pragma unroll
    for (int i = 0; i < 8; ++i) {
      int r = sr0 + 16 * i;
      rmask[i] = (want < 0 || flags[brow + r] == want) ? 1.f : 0.f;
    }

#pragma unroll 1
    for (int k0 = 0; k0 < DIM; k0 += BK) {
      __syncthreads();
      // stage A: f32 -> bf16 with per-row branch mask
#pragma unroll
      for (int i = 0; i < 8; ++i) {
        int r = sr0 + 16 * i;
        f32x4 v = *(const f32x4*)(Asrc + (size_t)(brow + r) * DIM + k0 + sc * 4);
        float msk = rmask[i];
        unsigned int lo = pack_bf2(v.x * msk, v.y * msk);
        unsigned int hi = pack_bf2(v.z * msk, v.w * msk);
        int off = r * (BK * 2) + ((sc * 8) ^ ((r & 7) << 4));
        *(uint2*)(sA + off) = uint2{lo, hi};
      }
      // stage B: bf16 16B vector copy
#pragma unroll
      for (int i = 0; i < 4; ++i) {
        int ch = t + 256 * i;
        int r = ch >> 3;
        int c = ch & 7;
        uint4 v = *(const uint4*)(Bsrc + (size_t)(bcol + r) * DIM + k0 + c * 8);
        int off = r * (BK * 2) + ((c * 16) ^ ((r & 7) << 4));
        *(uint4*)(sB + off) = v;
      }
      __syncthreads();
      // compute
      bf16x8 aF[4][2], bF[4][2];
#pragma unroll
      for (int m = 0; m < 4; ++m)
#pragma unroll
        for (int kk = 0; kk < 2; ++kk) {
          aF[m][kk] = *(const bf16x8*)(sA + aOff[m][kk]);
          bF[m][kk] = *(const bf16x8*)(sB + bOff[m][kk]);
        }
#pragma unroll
      for (int kk = 0; kk < 2; ++kk)
#pragma unroll
        for (int m = 0; m < 4; ++m)
#pragma unroll
          for (int n = 0; n < 4; ++n)
            acc[m][n] = __builtin_amdgcn_mfma_f32_16x16x32_bf16(
                aF[m][kk], bF[n][kk], acc[m][n], 0, 0, 0);
    }
  }

  // epilogue: C mapping col=lane&15, row=(lane>>4)*4+j; add h for pass rows
#pragma unroll
  for (int m = 0; m < 4; ++m) {
    int rbase = brow + wrow + m * 16 + (lane >> 4) * 4;
#pragma unroll
    for (int j = 0; j < 4; ++j) {
      int row = rbase + j;
      bool pass = (flags[row] == 2);
#pragma unroll
      for (int n = 0; n < 4; ++n) {
        int col = bcol + wcol + n * 16 + (lane & 15);
        float v = acc[m][n][j];
        if (pass) v += h[(size_t)row * DIM + col];
        out[(size_t)row * DIM + col] = v;
      }
    }
  }
}

extern "C" void kernel_launch(void* const* d_in, const int* in_sizes, int n_in,
                              void* d_out, int out_size, void* d_ws, size_t ws_size,
                              hipStream_t stream) {
  const float* x = (const float*)d_in[0];
  const float* h = (const float*)d_in[1];
  const float* W_ih = (const float*)d_in[2];
  const float* W_hh = (const float*)d_in[3];
  const float* W_inv = (const float*)d_in[4];
  float* out = (float*)d_out;

  char* ws = (char*)d_ws;
  int* flags = (int*)ws;                                      // 64 KB
  unsigned short* WihB = (unsigned short*)(ws + (64 << 10));  // 8 MB
  unsigned short* WhhT = WihB + (size_t)DIM * DIM;            // 8 MB
  unsigned short* WinvT = WhhT + (size_t)DIM * DIM;           // 8 MB

  k_flags<<<B_ROWS / 4, 256, 0, stream>>>(x, h, W_ih, flags);
  k_convert<<<(DIM * DIM / 4) / 256, 256, 0, stream>>>(W_ih, WihB);
  k_transpose<<<dim3(DIM / 32, DIM / 32), 256, 0, stream>>>(W_hh, WhhT);
  k_transpose<<<dim3(DIM / 32, DIM / 32), 256, 0, stream>>>(W_inv, WinvT);
  k_gemm<<<(B_ROWS / BM) * (DIM / BN), 256, 0, stream>>>(x, h, WihB, WhhT, WinvT,
                                                         flags, out);
}

// Round 2
// 596.166 us; speedup vs baseline: 1.3072x; 1.3072x over previous
//
#include <hip/hip_runtime.h>
#include <hip/hip_bf16.h>
#include <stdint.h>

#define B_ROWS 16384
#define DIM 2048
#define BM 128
#define BN 128
#define BK 64

typedef float f32x4 __attribute__((ext_vector_type(4)));
typedef short bf16x8 __attribute__((ext_vector_type(8)));
using u16 = unsigned short;
using u32 = unsigned int;

__device__ __forceinline__ u32 pack_bf2(float a, float b) {
  __hip_bfloat162 t = __float22bfloat162_rn(float2{a, b});
  union { __hip_bfloat162 b2; u32 u; } cv;
  cv.b2 = t;
  return cv.u;
}

__device__ __forceinline__ u16 f2bf_rne(float f) {
  union { float f; u32 u; } v;
  v.f = f;
  u32 u = v.u;
  u32 r = u + 0x7FFFu + ((u >> 16) & 1u);
  return (u16)(r >> 16);
}

__device__ __forceinline__ void gload16(const void* g, void* l) {
  __builtin_amdgcn_global_load_lds(
      (const __attribute__((address_space(1))) u32*)g,
      (__attribute__((address_space(3))) u32*)l, 16, 0, 0);
}

// ---- kernel 1a: flags (fp64-exact last-col dot) + x -> bf16 convert --------
__global__ __launch_bounds__(256) void k_flags_convx(
    const float* __restrict__ x, const float* __restrict__ h,
    const float* __restrict__ W_ih, int* __restrict__ flags,
    u16* __restrict__ xb) {
  int row = blockIdx.x * 4 + (threadIdx.x >> 6);
  int lane = threadIdx.x & 63;
  const float* xr = x + (size_t)row * DIM;
  const float* wr = W_ih + (size_t)(DIM - 1) * DIM;
  u16* xbr = xb + (size_t)row * DIM;
  double s = 0.0;
#pragma unroll
  for (int i = 0; i < 8; ++i) {
    int idx = (i * 64 + lane) * 4;
    f32x4 xv = *(const f32x4*)(xr + idx);
    f32x4 wv = *(const f32x4*)(wr + idx);
    s += (double)xv.x * wv.x + (double)xv.y * wv.y +
         (double)xv.z * wv.z + (double)xv.w * wv.w;
    *(uint2*)(xbr + idx) = uint2{pack_bf2(xv.x, xv.y), pack_bf2(xv.z, xv.w)};
  }
#pragma unroll
  for (int off = 32; off > 0; off >>= 1) s += __shfl_xor(s, off);
  if (lane == 0) {
    bool not_trig = (s >= -1.0);
    float hl = h[(size_t)row * DIM + (DIM - 1)];
    int f;
    if (!not_trig) f = 2;
    else if (hl > 0.f) f = 0;
    else if (hl < 0.f) f = 1;
    else f = 3;
    flags[row] = f;
  }
}

// ---- kernel 1b: flags only (fallback path) ---------------------------------
__global__ __launch_bounds__(256) void k_flags_fb(
    const float* __restrict__ x, const float* __restrict__ h,
    const float* __restrict__ W_ih, int* __restrict__ flags) {
  int row = blockIdx.x * 4 + (threadIdx.x >> 6);
  int lane = threadIdx.x & 63;
  const float* xr = x + (size_t)row * DIM;
  const float* wr = W_ih + (size_t)(DIM - 1) * DIM;
  double s = 0.0;
#pragma unroll
  for (int i = 0; i < 8; ++i) {
    int idx = (i * 64 + lane) * 4;
    f32x4 xv = *(const f32x4*)(xr + idx);
    f32x4 wv = *(const f32x4*)(wr + idx);
    s += (double)xv.x * wv.x + (double)xv.y * wv.y +
         (double)xv.z * wv.z + (double)xv.w * wv.w;
  }
#pragma unroll
  for (int off = 32; off > 0; off >>= 1) s += __shfl_xor(s, off);
  if (lane == 0) {
    bool not_trig = (s >= -1.0);
    float hl = h[(size_t)row * DIM + (DIM - 1)];
    int f;
    if (!not_trig) f = 2;
    else if (hl > 0.f) f = 0;
    else if (hl < 0.f) f = 1;
    else f = 3;
    flags[row] = f;
  }
}

// ---- kernel 2: h -> masked bf16 copies hFwd/hInv ---------------------------
__global__ __launch_bounds__(256) void k_maskh(const float* __restrict__ h,
                                               const int* __restrict__ flags,
                                               u16* __restrict__ hF,
                                               u16* __restrict__ hI) {
  size_t i = ((size_t)blockIdx.x * 256 + threadIdx.x) * 8;
  int row = (int)(i >> 11);
  int f = flags[row];
  f32x4 a = *(const f32x4*)(h + i);
  f32x4 b = *(const f32x4*)(h + i + 4);
  uint4 p = {pack_bf2(a.x, a.y), pack_bf2(a.z, a.w),
             pack_bf2(b.x, b.y), pack_bf2(b.z, b.w)};
  uint4 z = {0u, 0u, 0u, 0u};
  *(uint4*)(hF + i) = (f == 0) ? p : z;
  *(uint4*)(hI + i) = (f == 1) ? p : z;
}

// ---- kernel 3: convert W_ih ([N][K] already) f32 -> bf16 -------------------
__global__ __launch_bounds__(256) void k_convert(const float* __restrict__ src,
                                                 u16* __restrict__ dst) {
  size_t i = ((size_t)blockIdx.x * 256 + threadIdx.x) * 4;
  f32x4 v = *(const f32x4*)(src + i);
  *(uint2*)(dst + i) = uint2{pack_bf2(v.x, v.y), pack_bf2(v.z, v.w)};
}

// ---- kernel 4: transpose+convert [K][N] f32 -> [N][K] bf16 -----------------
__global__ __launch_bounds__(256) void k_transpose(const float* __restrict__ src,
                                                   u16* __restrict__ dst) {
  __shared__ float tile[32][33];
  int k0 = blockIdx.x * 32;
  int n0 = blockIdx.y * 32;
  int tx = threadIdx.x & 31;
  int ty = threadIdx.x >> 5;
#pragma unroll
  for (int i = 0; i < 4; ++i)
    tile[ty + 8 * i][tx] = src[(size_t)(k0 + ty + 8 * i) * DIM + n0 + tx];
  __syncthreads();
#pragma unroll
  for (int i = 0; i < 4; ++i)
    dst[(size_t)(n0 + ty + 8 * i) * DIM + k0 + tx] = f2bf_rne(tile[tx][ty + 8 * i]);
}

// ---- kernel 5 (fast): pure-bf16 3-segment GEMM via global_load_lds ---------
// LDS linear; swizzle done by XOR on the per-lane GLOBAL source chunk (m173).
__global__ __launch_bounds__(256, 2) void k_gemm_fast(
    const u16* __restrict__ xb, const u16* __restrict__ hF,
    const u16* __restrict__ hI, const u16* __restrict__ Wih,
    const u16* __restrict__ WhhT, const u16* __restrict__ WinvT,
    const int* __restrict__ flags, const float* __restrict__ h,
    float* __restrict__ out) {
  __shared__ char smem[(BM + BN) * BK * 2];  // 32 KB
  char* sA = smem;
  char* sB = smem + BM * BK * 2;

  int o = blockIdx.x;
  int swz = (o & 7) * ((int)gridDim.x >> 3) + (o >> 3);
  int brow = (swz >> 4) * BM;
  int bcol = (swz & 15) * BN;

  int t = threadIdx.x;
  int lane = t & 63;
  int wave = t >> 6;
  int wrow = (wave >> 1) * 64;
  int wcol = (wave & 1) * 64;

  f32x4 acc[4][4] = {};

  // fragment LDS byte offsets (XOR swizzle: byte ^= (row&7)<<4)
  int aOff[4][2], bOff[4][2];
#pragma unroll
  for (int m = 0; m < 4; ++m)
#pragma unroll
    for (int kk = 0; kk < 2; ++kk) {
      int ar = wrow + m * 16 + (lane & 15);
      aOff[m][kk] = ar * (BK * 2) + ((kk * 64 + (lane >> 4) * 16) ^ ((ar & 7) << 4));
      int br = wcol + m * 16 + (lane & 15);
      bOff[m][kk] = br * (BK * 2) + ((kk * 64 + (lane >> 4) * 16) ^ ((br & 7) << 4));
    }

  // staging geometry: per wave 4 insts, 8 rows each; lane l -> row +l>>3, chunk l&7
  int srow = lane >> 3;            // 0..7, == (row&7) for our row bases
  int schunk = lane & 7;
  int sxor = (schunk * 16) ^ (srow << 4);

#pragma unroll 1
  for (int seg = 0; seg < 3; ++seg) {
    const u16* Ab = (seg == 0) ? xb : (seg == 1) ? hF : hI;
    const u16* Bb = (seg == 0) ? Wih : (seg == 1) ? WhhT : WinvT;
    const char* Abase = (const char*)(Ab + (size_t)brow * DIM);
    const char* Bbase = (const char*)(Bb + (size_t)bcol * DIM);

#pragma unroll 1
    for (int k0 = 0; k0 < DIM; k0 += BK) {
      __syncthreads();
#pragma unroll
      for (int i = 0; i < 4; ++i) {
        int rbase = i * 32 + wave * 8;
        size_t roff = (size_t)(rbase + srow) * (DIM * 2) + (size_t)(k0 * 2) + sxor;
        gload16(Abase + roff, sA + rbase * (BK * 2));
        gload16(Bbase + roff, sB + rbase * (BK * 2));
      }
      __syncthreads();
      bf16x8 aF[4][2], bF[4][2];
#pragma unroll
      for (int m = 0; m < 4; ++m)
#pragma unroll
        for (int kk = 0; kk < 2; ++kk) {
          aF[m][kk] = *(const bf16x8*)(sA + aOff[m][kk]);
          bF[m][kk] = *(const bf16x8*)(sB + bOff[m][kk]);
        }
#pragma unroll
      for (int kk = 0; kk < 2; ++kk)
#pragma unroll
        for (int m = 0; m < 4; ++m)
#pragma unroll
          for (int n = 0; n < 4; ++n)
            acc[m][n] = __builtin_amdgcn_mfma_f32_16x16x32_bf16(
                aF[m][kk], bF[n][kk], acc[m][n], 0, 0, 0);
    }
  }

#pragma unroll
  for (int m = 0; m < 4; ++m) {
    int rbase = brow + wrow + m * 16 + (lane >> 4) * 4;
#pragma unroll
    for (int j = 0; j < 4; ++j) {
      int row = rbase + j;
      bool pass = (flags[row] == 2);
#pragma unroll
      for (int n = 0; n < 4; ++n) {
        int col = bcol + wcol + n * 16 + (lane & 15);
        float v = acc[m][n][j];
        if (pass) v += h[(size_t)row * DIM + col];
        out[(size_t)row * DIM + col] = v;
      }
    }
  }
}

// ---- kernel 5 (fallback, ws-small): R1 reg-staged masked GEMM --------------
__global__ __launch_bounds__(256, 2) void k_gemm_fb(
    const float* __restrict__ x, const float* __restrict__ h,
    const u16* __restrict__ Wih, const u16* __restrict__ WhhT,
    const u16* __restrict__ WinvT, const int* __restrict__ flags,
    float* __restrict__ out) {
  __shared__ char smem[(BM + BN) * BK * 2];
  char* sA = smem;
  char* sB = smem + BM * BK * 2;

  int o = blockIdx.x;
  int swz = (o & 7) * ((int)gridDim.x >> 3) + (o >> 3);
  int brow = (swz >> 4) * BM;
  int bcol = (swz & 15) * BN;

  int t = threadIdx.x;
  int lane = t & 63;
  int wave = t >> 6;
  int wrow = (wave >> 1) * 64;
  int wcol = (wave & 1) * 64;

  f32x4 acc[4][4] = {};
  int sc = t & 15;
  int sr0 = t >> 4;

  int aOff[4][2], bOff[4][2];
#pragma unroll
  for (int m = 0; m < 4; ++m)
#pragma unroll
    for (int kk = 0; kk < 2; ++kk) {
      int ar = wrow + m * 16 + (lane & 15);
      aOff[m][kk] = ar * (BK * 2) + ((kk * 64 + (lane >> 4) * 16) ^ ((ar & 7) << 4));
      int br = wcol + m * 16 + (lane & 15);
      bOff[m][kk] = br * (BK * 2) + ((kk * 64 + (lane >> 4) * 16) ^ ((br & 7) << 4));
    }

#pragma unroll 1
  for (int seg = 0; seg < 3; ++seg) {
    const float* Asrc = (seg == 0) ? x : h;
    const u16* Bsrc = (seg == 0) ? Wih : (seg == 1) ? WhhT : WinvT;
    int want = seg - 1;

    float rmask[8];
#pragma unroll
    for (int i = 0; i < 8; ++i) {
      int r = sr0 + 16 * i;
      rmask[i] = (want < 0 || flags[brow + r] == want) ? 1.f : 0.f;
    }

#pragma unroll 1
    for (int k0 = 0; k0 < DIM; k0 += BK) {
      __syncthreads();
#pragma unroll
      for (int i = 0; i < 8; ++i) {
        int r = sr0 + 16 * i;
        f32x4 v = *(const f32x4*)(Asrc + (size_t)(brow + r) * DIM + k0 + sc * 4);
        float msk = rmask[i];
        int off = r * (BK * 2) + ((sc * 8) ^ ((r & 7) << 4));
        *(uint2*)(sA + off) =
            uint2{pack_bf2(v.x * msk, v.y * msk), pack_bf2(v.z * msk, v.w * msk)};
      }
#pragma unroll
      for (int i = 0; i < 4; ++i) {
        int ch = t + 256 * i;
        int r = ch >> 3;
        int c = ch & 7;
        uint4 v = *(const uint4*)(Bsrc + (size_t)(bcol + r) * DIM + k0 + c * 8);
        int off = r * (BK * 2) + ((c * 16) ^ ((r & 7) << 4));
        *(uint4*)(sB + off) = v;
      }
      __syncthreads();
      bf16x8 aF[4][2], bF[4][2];
#pragma unroll
      for (int m = 0; m < 4; ++m)
#pragma unroll
        for (int kk = 0; kk < 2; ++kk) {
          aF[m][kk] = *(const bf16x8*)(sA + aOff[m][kk]);
          bF[m][kk] = *(const bf16x8*)(sB + bOff[m][kk]);
        }
#pragma unroll
      for (int kk = 0; kk < 2; ++kk)
#pragma unroll
        for (int m = 0; m < 4; ++m)
#pragma unroll
          for (int n = 0; n < 4; ++n)
            acc[m][n] = __builtin_amdgcn_mfma_f32_16x16x32_bf16(
                aF[m][kk], bF[n][kk], acc[m][n], 0, 0, 0);
    }
  }

#pragma unroll
  for (int m = 0; m < 4; ++m) {
    int rbase = brow + wrow + m * 16 + (lane >> 4) * 4;
#pragma unroll
    for (int j = 0; j < 4; ++j) {
      int row = rbase + j;
      bool pass = (flags[row] == 2);
#pragma unroll
      for (int n = 0; n < 4; ++n) {
        int col = bcol + wcol + n * 16 + (lane & 15);
        float v = acc[m][n][j];
        if (pass) v += h[(size_t)row * DIM + col];
        out[(size_t)row * DIM + col] = v;
      }
    }
  }
}

extern "C" void kernel_launch(void* const* d_in, const int* in_sizes, int n_in,
                              void* d_out, int out_size, void* d_ws, size_t ws_size,
                              hipStream_t stream) {
  const float* x = (const float*)d_in[0];
  const float* h = (const float*)d_in[1];
  const float* W_ih = (const float*)d_in[2];
  const float* W_hh = (const float*)d_in[3];
  const float* W_inv = (const float*)d_in[4];
  float* out = (float*)d_out;

  char* ws = (char*)d_ws;
  int* flags = (int*)ws;                                       // 64 KB
  u16* WihB = (u16*)(ws + (64 << 10));                         // 8 MB
  u16* WhhT = WihB + (size_t)DIM * DIM;                        // 8 MB
  u16* WinvT = WhhT + (size_t)DIM * DIM;                       // 8 MB
  u16* xb = WinvT + (size_t)DIM * DIM;                         // 64 MB
  u16* hF = xb + (size_t)B_ROWS * DIM;                         // 64 MB
  u16* hI = hF + (size_t)B_ROWS * DIM;                         // 64 MB
  size_t need = (size_t)(64 << 10) + 3u * DIM * DIM * 2 + 3ull * B_ROWS * DIM * 2;

  k_convert<<<(DIM * DIM / 4) / 256, 256, 0, stream>>>(W_ih, WihB);
  k_transpose<<<dim3(DIM / 32, DIM / 32), 256, 0, stream>>>(W_hh, WhhT);
  k_transpose<<<dim3(DIM / 32, DIM / 32), 256, 0, stream>>>(W_inv, WinvT);

  if (ws_size >= need) {
    k_flags_convx<<<B_ROWS / 4, 256, 0, stream>>>(x, h, W_ih, flags, xb);
    k_maskh<<<(B_ROWS * (DIM / 8)) / 256, 256, 0, stream>>>(h, flags, hF, hI);
    k_gemm_fast<<<(B_ROWS / BM) * (DIM / BN), 256, 0, stream>>>(
        xb, hF, hI, WihB, WhhT, WinvT, flags, h, out);
  } else {
    k_flags_fb<<<B_ROWS / 4, 256, 0, stream>>>(x, h, W_ih, flags);
    k_gemm_fb<<<(B_ROWS / BM) * (DIM / BN), 256, 0, stream>>>(x, h, WihB, WhhT,
                                                              WinvT, flags, out);
  }
}